// Round 6
// baseline (400.054 us; speedup 1.0000x reference)
//
#include <hip/hip_runtime.h>
#include <hip/hip_cooperative_groups.h>

namespace cg = cooperative_groups;

#define N_NODES 50000
#define N_EDGES 800000
#define D 96
#define D4 (D / 4)        // 24 float4 per row

#define RL 12             // bf16 row = 96*2B = 12 uint4 per node row
#define HPAD 13           // LDS h-row stride in uint4 (kills bank conflicts)

// ---- counting-sort geometry ----
#define NB 196            // buckets of 256 nodes (ceil(50000/256))
#define ECAP 5120         // per-bucket dst-edge capacity (mean 4081, +16 sigma)
#define SCAP 5120         // per-bucket src-entry capacity (same stats)
#define CCAP 6144         // per-bucket padded-CSR capacity u16 (mean ~5050, +16 sigma)
#define PA_CHUNK 3125     // 256 * 3125 = 800000 exact (R3-verified geometry)
#define GRID_BLKS 256
#define NT 3125           // 16-row output tiles (50000/16)

typedef __attribute__((ext_vector_type(8))) short short8;
typedef __attribute__((ext_vector_type(4))) float floatx4;

__device__ __forceinline__ short8 as_short8(uint4 u) { return *(short8*)&u; }

// bf16 RTNE pack: a -> low 16, b -> high 16.
__device__ __forceinline__ unsigned bf16pack(float a, float b) {
    unsigned ua = __float_as_uint(a);
    unsigned ub = __float_as_uint(b);
    ua = (ua + 0x7FFFu + ((ua >> 16) & 1u)) >> 16;       // RTNE
    ub = (ub + 0x7FFFu + ((ub >> 16) & 1u)) & 0xFFFF0000u;
    return ua | ub;
}

// Fully fused pipeline: phase A (dual-key bucket partition, R3-verified
// geometry) -> grid sync -> phase B (per-bucket CSR build + deg + fused conv
// + WT prep, R5-verified) -> grid sync -> phase C (gather+MFMA, R3-verified
// 192-thread tile groups x5 per block x3 sweeps). One dispatch instead of 4:
// eliminates inter-dispatch gaps and makes the whole pipeline visible as a
// single >46us entry in rocprof (previously hidden under poison fills).
__global__ void __launch_bounds__(1024) fused_kernel(
        const int* __restrict__ src, const int* __restrict__ dst,
        const float4* __restrict__ feat4, const float* __restrict__ W,
        const float* __restrict__ bias,
        unsigned* __restrict__ gcur, unsigned* __restrict__ ebuf,
        unsigned short* __restrict__ sbuf, unsigned short* __restrict__ csr,
        uint4* __restrict__ sfeat, unsigned* __restrict__ WT32,
        int* __restrict__ deg_in, int* __restrict__ off,
        float* __restrict__ out) {
    // phase-union scratch: A needs 41.6KB, B 35.9KB, C 16.7KB
    __shared__ __align__(16) char smem[41600];
    __shared__ unsigned wsum8[8];
    __shared__ unsigned tot_s;
    cg::grid_group grid = cg::this_grid();
    int t = threadIdx.x;
    int blk = blockIdx.x;

    // ================= Phase A: dual-key bucket partition =================
    {
        unsigned*       raw    = (unsigned*)(smem);            // 3125 u32
        unsigned*       ord    = (unsigned*)(smem + 12544);    // 3125 u32
        unsigned short* sord   = (unsigned short*)(smem + 25088); // 3125 u16
        unsigned*       hist   = (unsigned*)(smem + 31360);    // 512 u32
        unsigned*       lstart = (unsigned*)(smem + 35456);    // 512
        unsigned*       cur    = (unsigned*)(smem + 37504);    // 512
        unsigned*       gbase  = (unsigned*)(smem + 39552);    // 512
        int e0 = blk * PA_CHUNK;
        if (t < 512) hist[t] = 0;
        __syncthreads();
        for (int i = t; i < PA_CHUNK; i += 1024) {
            int s = src[e0 + i];
            int d = dst[e0 + i];
            raw[i] = ((unsigned)d << 16) | (unsigned)s;
            atomicAdd(&hist[d >> 8], 1u);
            atomicAdd(&hist[256 + (s >> 8)], 1u);
        }
        __syncthreads();
        // two independent 256-entry scans via shfl (4 barriers vs 16)
        unsigned h = 0, incl = 0;
        if (t < 512) {
            h = hist[t];
            incl = h;
            int lane = t & 63;
#pragma unroll
            for (int st = 1; st < 64; st <<= 1) {
                unsigned u = __shfl_up(incl, st, 64);
                if (lane >= st) incl += u;
            }
            if (lane == 63) wsum8[t >> 6] = incl;
        }
        __syncthreads();
        if (t < 512) {
            int w = t >> 6;            // global wave id 0..7
            int h0 = (t >> 8) * 4;     // first wave of this 256-half
            unsigned base = 0;
            for (int k = h0; k < w; ++k) base += wsum8[k];
            incl += base;
            unsigned ls = incl - h;    // exclusive within half
            lstart[t] = ls;
            cur[t] = ls;
            if ((t & 255) < NB)
                gbase[t] = atomicAdd(&gcur[(t >> 8) * NB + (t & 255)], h);
        }
        __syncthreads();
        for (int i = t; i < PA_CHUNK; i += 1024) {   // LDS scatter into bucket order
            unsigned r = raw[i];
            unsigned p = atomicAdd(&cur[r >> 24], 1u);        // dst bucket
            ord[p] = r;
            unsigned s = r & 0xFFFFu;
            unsigned q = atomicAdd(&cur[256 + (s >> 8)], 1u); // src bucket
            sord[q] = (unsigned short)s;
        }
        __syncthreads();
        for (int i = t; i < PA_CHUNK; i += 1024) {   // coalesced-run copy-out
            unsigned r = ord[i];
            unsigned bd = r >> 24;
            unsigned pos = gbase[bd] + ((unsigned)i - lstart[bd]);
            if (pos < ECAP) ebuf[bd * ECAP + pos] = r;
            unsigned s = sord[i];
            unsigned bs = 256 + (s >> 8);
            unsigned pos2 = gbase[bs] + ((unsigned)i - lstart[bs]);
            if (pos2 < SCAP) sbuf[(size_t)(bs - 256) * SCAP + pos2] = (unsigned short)s;
        }
    }
    __threadfence();
    grid.sync();

    // ====== Phase B: CSR build + deg_in + fused conv (b<NB) / WT prep ======
    if (blk < NB) {
        unsigned*       eb     = (unsigned*)(smem);            // 5120 u32
        unsigned short* csr_l  = (unsigned short*)(smem + 20480); // 6144 u16
        unsigned*       dcount = (unsigned*)(smem + 32768);    // 256
        unsigned*       dcur   = (unsigned*)(smem + 33792);    // 256
        unsigned*       scount = (unsigned*)(smem + 34816);    // 256
        int b = blk;
        unsigned cntd = gcur[b];      if (cntd > ECAP) cntd = ECAP;
        unsigned cnts = gcur[NB + b]; if (cnts > SCAP) cnts = SCAP;
        if (t < 256) { dcount[t] = 0; scount[t] = 0; }
        __syncthreads();
        const unsigned* __restrict__ sg = ebuf + (size_t)b * ECAP;
        for (int i = t; i < (int)cntd; i += 1024) {
            unsigned r = sg[i];
            eb[i] = r;
            atomicAdd(&dcount[(r >> 16) & 255u], 1u);
        }
        const unsigned short* __restrict__ ss = sbuf + (size_t)b * SCAP;
        for (int i = t; i < (int)cnts; i += 1024)
            atomicAdd(&scount[ss[i] & 255u], 1u);
        __syncthreads();
        // 3-barrier shfl scan of 8-padded sizes (threads 0..255 = 4 waves)
        unsigned pad = 0, incl = 0;
        if (t < 256) {
            pad = (dcount[t] + 7u) & ~7u;
            incl = pad;
            int lane = t & 63;
#pragma unroll
            for (int st = 1; st < 64; st <<= 1) {
                unsigned u = __shfl_up(incl, st, 64);
                if (lane >= st) incl += u;
            }
            if (lane == 63) wsum8[t >> 6] = incl;
        }
        __syncthreads();
        if (t < 256) {
            int w = t >> 6;
            unsigned base = 0;
            for (int k = 0; k < w; ++k) base += wsum8[k];
            incl += base;
            unsigned ex = incl - pad;               // exclusive padded
            dcur[t] = ex;
            if (t == 255) tot_s = incl;
            int n = b * 256 + t;
            if (n < N_NODES) {
                deg_in[n] = (int)dcount[t];
                off[n] = b * CCAP + (int)ex;
            }
        }
        __syncthreads();
        for (int i = t; i < (int)cntd; i += 1024) {   // CSR scatter from LDS stage
            unsigned r = eb[i];
            unsigned p = atomicAdd(&dcur[(r >> 16) & 255u], 1u);
            if (p < CCAP) csr_l[p] = (unsigned short)(r & 0xFFFFu);
        }
        __syncthreads();
        unsigned tot = tot_s;
        if (tot > CCAP) tot = CCAP;
        unsigned* __restrict__ og = (unsigned*)(csr + (size_t)b * CCAP);
        const unsigned* __restrict__ cl = (const unsigned*)csr_l;
        for (int i = t; i < (int)(tot >> 1); i += 1024) og[i] = cl[i];
        // fused conv: sfeat rows for the 256 owned nodes
        for (int r2 = t; r2 < 256 * RL; r2 += 1024) {
            int nl = r2 / RL;
            int lane = r2 - nl * RL;
            int n = b * 256 + nl;
            if (n < N_NODES) {
                float c = rsqrtf(fmaxf((float)scount[nl], 1.0f));
                float4 a = feat4[(size_t)n * D4 + lane * 2];
                float4 bb = feat4[(size_t)n * D4 + lane * 2 + 1];
                uint4 o;
                o.x = bf16pack(a.x * c, a.y * c);
                o.y = bf16pack(a.z * c, a.w * c);
                o.z = bf16pack(bb.x * c, bb.y * c);
                o.w = bf16pack(bb.z * c, bb.w * c);
                sfeat[(size_t)n * RL + lane] = o;
            }
        }
    } else {   // WT prep on blocks 196..255
        int t2 = (blk - NB) * 1024 + t;
        if (t2 < D * (D / 2)) {
            int n = t2 / (D / 2);
            int j = t2 - n * (D / 2);
            float w0 = W[(2 * j) * D + n];
            float w1 = W[(2 * j + 1) * D + n];
            WT32[n * (D / 2) + j] = bf16pack(w0, w1);
        }
    }
    __threadfence();
    grid.sync();

    // ================= Phase C: gather + MFMA =================
    {
        const uint4* __restrict__ wt4 = (const uint4*)WT32;
        int grp = t / 192;           // 0..4 active groups; 5 = spare threads
        int r = t - grp * 192;
        uint4* shg = (uint4*)(smem + grp * 3328);   // 16*HPAD uint4 per group
        for (int j = 0; j < 3; ++j) {
            int tile = j * 1280 + blk * 5 + grp;
            bool active = (t < 960) && (tile < NT);
            int deg = 0;
            if (active) {   // ---- gather (R3-verified body) ----
                int g = r / RL;
                int lane = r - g * RL;
                int n = tile * 16 + g;
                deg = deg_in[n];
                uint4* __restrict__ hout = &shg[g * HPAD + lane];
                if (deg == 0) {
                    float4 a = feat4[(size_t)n * D4 + lane * 2];
                    float4 b = feat4[(size_t)n * D4 + lane * 2 + 1];
                    uint4 o;
                    o.x = bf16pack(a.x, a.y);
                    o.y = bf16pack(a.z, a.w);
                    o.z = bf16pack(b.x, b.y);
                    o.w = bf16pack(b.z, b.w);
                    *hout = o;
                } else {
                    const unsigned short* __restrict__ bk = csr + off[n];
                    const uint4* __restrict__ sf = sfeat + lane;
                    float acc[8] = {};
#define ACC8(v)  { \
        acc[0] += __uint_as_float((v).x << 16); \
        acc[1] += __uint_as_float((v).x & 0xFFFF0000u); \
        acc[2] += __uint_as_float((v).y << 16); \
        acc[3] += __uint_as_float((v).y & 0xFFFF0000u); \
        acc[4] += __uint_as_float((v).z << 16); \
        acc[5] += __uint_as_float((v).z & 0xFFFF0000u); \
        acc[6] += __uint_as_float((v).w << 16); \
        acc[7] += __uint_as_float((v).w & 0xFFFF0000u); }
                    int i = 0;
                    int full16 = deg & ~15;
                    for (; i < full16; i += 16) {
                        uint4 ia = *(const uint4*)(bk + i);
                        uint4 ib = *(const uint4*)(bk + i + 8);
                        unsigned s0 = ia.x & 0xFFFFu, s1 = ia.x >> 16;
                        unsigned s2 = ia.y & 0xFFFFu, s3 = ia.y >> 16;
                        unsigned s4 = ia.z & 0xFFFFu, s5 = ia.z >> 16;
                        unsigned s6 = ia.w & 0xFFFFu, s7 = ia.w >> 16;
                        unsigned s8 = ib.x & 0xFFFFu, s9 = ib.x >> 16;
                        unsigned sa = ib.y & 0xFFFFu, sb = ib.y >> 16;
                        unsigned sx = ib.z & 0xFFFFu, sd = ib.z >> 16;
                        unsigned se = ib.w & 0xFFFFu, sfi = ib.w >> 16;
                        uint4 v0 = sf[(size_t)s0 * RL];
                        uint4 v1 = sf[(size_t)s1 * RL];
                        uint4 v2 = sf[(size_t)s2 * RL];
                        uint4 v3 = sf[(size_t)s3 * RL];
                        uint4 v4 = sf[(size_t)s4 * RL];
                        uint4 v5 = sf[(size_t)s5 * RL];
                        uint4 v6 = sf[(size_t)s6 * RL];
                        uint4 v7 = sf[(size_t)s7 * RL];
                        uint4 v8 = sf[(size_t)s8 * RL];
                        uint4 v9 = sf[(size_t)s9 * RL];
                        uint4 va = sf[(size_t)sa * RL];
                        uint4 vb = sf[(size_t)sb * RL];
                        uint4 vc = sf[(size_t)sx * RL];
                        uint4 vd = sf[(size_t)sd * RL];
                        uint4 ve = sf[(size_t)se * RL];
                        uint4 vf = sf[(size_t)sfi * RL];
                        ACC8(v0); ACC8(v1); ACC8(v2); ACC8(v3);
                        ACC8(v4); ACC8(v5); ACC8(v6); ACC8(v7);
                        ACC8(v8); ACC8(v9); ACC8(va); ACC8(vb);
                        ACC8(vc); ACC8(vd); ACC8(ve); ACC8(vf);
                    }
                    int full8 = deg & ~7;
                    for (; i < full8; i += 8) {
                        uint4 idx = *(const uint4*)(bk + i);
                        unsigned s0 = idx.x & 0xFFFFu, s1 = idx.x >> 16;
                        unsigned s2 = idx.y & 0xFFFFu, s3 = idx.y >> 16;
                        unsigned s4 = idx.z & 0xFFFFu, s5 = idx.z >> 16;
                        unsigned s6 = idx.w & 0xFFFFu, s7 = idx.w >> 16;
                        uint4 v0 = sf[(size_t)s0 * RL];
                        uint4 v1 = sf[(size_t)s1 * RL];
                        uint4 v2 = sf[(size_t)s2 * RL];
                        uint4 v3 = sf[(size_t)s3 * RL];
                        uint4 v4 = sf[(size_t)s4 * RL];
                        uint4 v5 = sf[(size_t)s5 * RL];
                        uint4 v6 = sf[(size_t)s6 * RL];
                        uint4 v7 = sf[(size_t)s7 * RL];
                        ACC8(v0); ACC8(v1); ACC8(v2); ACC8(v3);
                        ACC8(v4); ACC8(v5); ACC8(v6); ACC8(v7);
                    }
                    for (; i < deg; ++i) {
                        uint4 v = sf[(size_t)bk[i] * RL];
                        ACC8(v);
                    }
#undef ACC8
                    float cj = rsqrtf((float)deg);
                    uint4 o;
                    o.x = bf16pack(acc[0] * cj, acc[1] * cj);
                    o.y = bf16pack(acc[2] * cj, acc[3] * cj);
                    o.z = bf16pack(acc[4] * cj, acc[5] * cj);
                    o.w = bf16pack(acc[6] * cj, acc[7] * cj);
                    *hout = o;
                }
            }
            __syncthreads();
            if (active) {   // ---- MFMA (R3-verified: 3 waves x 2 col-tiles) ----
                int wave = r >> 6;
                int lane64 = r & 63;
                int m = lane64 & 15, quad = lane64 >> 4;
                short8 a0 = as_short8(shg[m * HPAD + quad]);       // k = 0..31
                short8 a1 = as_short8(shg[m * HPAD + 4 + quad]);   // k = 32..63
                short8 a2 = as_short8(shg[m * HPAD + 8 + quad]);   // k = 64..95
                int r_out0 = tile * 16 + quad * 4;
#pragma unroll
                for (int ct = wave * 2; ct < wave * 2 + 2; ++ct) {
                    int nn = ct * 16 + m;
                    int wb = nn * RL + quad;
                    short8 b0 = as_short8(wt4[wb]);
                    short8 b1 = as_short8(wt4[wb + 4]);
                    short8 b2 = as_short8(wt4[wb + 8]);
                    floatx4 c = {0.f, 0.f, 0.f, 0.f};
                    c = __builtin_amdgcn_mfma_f32_16x16x32_bf16(a0, b0, c, 0, 0, 0);
                    c = __builtin_amdgcn_mfma_f32_16x16x32_bf16(a1, b1, c, 0, 0, 0);
                    c = __builtin_amdgcn_mfma_f32_16x16x32_bf16(a2, b2, c, 0, 0, 0);
                    float bs = bias[nn];
#pragma unroll
                    for (int rr = 0; rr < 4; ++rr)
                        out[(size_t)(r_out0 + rr) * D + nn] = c[rr] + bs;
                }
            }
            __syncthreads();   // shg reused next sweep
        }
    }
}

extern "C" void kernel_launch(void* const* d_in, const int* in_sizes, int n_in,
                              void* d_out, int out_size, void* d_ws, size_t ws_size,
                              hipStream_t stream) {
    const int*    src   = (const int*)d_in[3];
    const int*    dst   = (const int*)d_in[4];
    const float4* feat4 = (const float4*)d_in[0];
    const float*  W     = (const float*)d_in[1];
    const float*  bias  = (const float*)d_in[2];

    // ws layout (~18.4 MB; every byte rewritten each call or never read):
    //   gcur[2*NB] | deg_in[N] | off[N] |
    //   ebuf u32 [NB][ECAP] 4.0MB | sbuf u16 [NB][SCAP] 2.0MB |
    //   csr u16 [NB][CCAP] 2.4MB | sfeat 9.6MB | WT 18KB
    unsigned*       gcur   = (unsigned*)d_ws;
    int*            deg_in = (int*)(gcur + 2 * NB);
    int*            off    = deg_in + N_NODES;
    unsigned*       ebuf   = (unsigned*)(off + N_NODES);
    unsigned short* sbuf   = (unsigned short*)(ebuf + (size_t)NB * ECAP);
    unsigned short* csr    = sbuf + (size_t)NB * SCAP;
    uint4*          sfeat  = (uint4*)(csr + (size_t)NB * CCAP);
    unsigned*       WT32   = (unsigned*)(sfeat + (size_t)N_NODES * RL);
    float*          out    = (float*)d_out;

    hipMemsetAsync(gcur, 0, 2 * NB * sizeof(unsigned), stream);
    void* args[] = {
        (void*)&src, (void*)&dst, (void*)&feat4, (void*)&W, (void*)&bias,
        (void*)&gcur, (void*)&ebuf, (void*)&sbuf, (void*)&csr,
        (void*)&sfeat, (void*)&WT32, (void*)&deg_in, (void*)&off, (void*)&out
    };
    hipLaunchCooperativeKernel((const void*)fused_kernel, dim3(GRID_BLKS),
                               dim3(1024), args, 0, stream);
}

// Round 7
// 137.095 us; speedup vs baseline: 2.9181x; 2.9181x over previous
//
#include <hip/hip_runtime.h>

#define N_NODES 50000
#define N_EDGES 800000
#define D 96
#define D4 (D / 4)        // 24 float4 per row

#define RL 12             // bf16 row = 96*2B = 12 uint4 per node row
#define HPAD 13           // LDS h-row stride in uint4 (kills bank conflicts)
#define CONV_BLOCKS ((N_NODES * RL + 255) / 256)   // 2344
#define WPREP_BLOCKS ((D * (D / 2) + 255) / 256)   // 18

// ---- counting-sort geometry (R2-verified: 138.8us run) ----
#define NB 196            // buckets of 256 nodes (ceil(50000/256))
#define ECAP 5120         // per-bucket dst-edge capacity (mean 4096, +16 sigma)
#define SCAP 5120         // per-bucket src-entry capacity (same stats)
#define CCAP 6144         // per-bucket padded-CSR capacity u16 (mean ~5100, +14 sigma)
#define PA_BLOCKS 256
#define PA_CHUNK 3125     // 256 * 3125 = 800000 exact

typedef __attribute__((ext_vector_type(8))) short short8;
typedef __attribute__((ext_vector_type(4))) float floatx4;

__device__ __forceinline__ short8 as_short8(uint4 u) { return *(short8*)&u; }

// bf16 RTNE pack: a -> low 16, b -> high 16.
__device__ __forceinline__ unsigned bf16pack(float a, float b) {
    unsigned ua = __float_as_uint(a);
    unsigned ub = __float_as_uint(b);
    ua = (ua + 0x7FFFu + ((ua >> 16) & 1u)) >> 16;       // RTNE
    ub = (ub + 0x7FFFu + ((ub >> 16) & 1u)) & 0xFFFF0000u;
    return ua | ub;
}

// Stage 1a: dual-key bucket partition (R2-verified structure; the only change
// vs the 138.8us run is the scan: 16-barrier Hillis-Steele -> 4-barrier dual
// shfl scan, bit-exact-verified in R6 phase A). Edges to dst-buckets (ebuf,
// (dst<<16)|src) AND src values to src-buckets (sbuf, u16). No global data
// atomics.
__global__ void __launch_bounds__(1024) sortA_kernel(
        const int* __restrict__ src, const int* __restrict__ dst,
        unsigned* __restrict__ gcur,       // [2*NB]: dst cursors | src cursors
        unsigned* __restrict__ ebuf, unsigned short* __restrict__ sbuf) {
    __shared__ unsigned raw[PA_CHUNK];          // 12.5 KB
    __shared__ unsigned ord[PA_CHUNK];          // 12.5 KB
    __shared__ unsigned short sord[PA_CHUNK];   // 6.25 KB
    __shared__ unsigned hist[512];   // [0..255] dst-buckets, [256..511] src-buckets
    __shared__ unsigned lstart[512], cur[512], gbase[512];
    __shared__ unsigned wsum8[8];
    int t = threadIdx.x;
    int e0 = blockIdx.x * PA_CHUNK;
    if (t < 512) hist[t] = 0;
    __syncthreads();
    for (int i = t; i < PA_CHUNK; i += 1024) {
        int s = src[e0 + i];
        int d = dst[e0 + i];
        raw[i] = ((unsigned)d << 16) | (unsigned)s;
        atomicAdd(&hist[d >> 8], 1u);
        atomicAdd(&hist[256 + (s >> 8)], 1u);
    }
    __syncthreads();
    // two independent 256-entry scans via shfl (4 barriers total vs 16)
    unsigned h = 0, incl = 0;
    if (t < 512) {
        h = hist[t];
        incl = h;
        int lane = t & 63;
#pragma unroll
        for (int st = 1; st < 64; st <<= 1) {
            unsigned u = __shfl_up(incl, st, 64);
            if (lane >= st) incl += u;
        }
        if (lane == 63) wsum8[t >> 6] = incl;
    }
    __syncthreads();
    if (t < 512) {
        int w = t >> 6;            // global wave id 0..7
        int h0 = (t >> 8) * 4;     // first wave of this 256-half
        unsigned base = 0;
        for (int k = h0; k < w; ++k) base += wsum8[k];
        incl += base;
        unsigned ls = incl - h;    // exclusive within half
        lstart[t] = ls;
        cur[t] = ls;
        if ((t & 255) < NB)
            gbase[t] = atomicAdd(&gcur[(t >> 8) * NB + (t & 255)], h);
    }
    __syncthreads();
    for (int i = t; i < PA_CHUNK; i += 1024) {   // LDS scatter into bucket order
        unsigned r = raw[i];
        unsigned p = atomicAdd(&cur[r >> 24], 1u);        // dst bucket
        ord[p] = r;
        unsigned s = r & 0xFFFFu;
        unsigned q = atomicAdd(&cur[256 + (s >> 8)], 1u); // src bucket
        sord[q] = (unsigned short)s;
    }
    __syncthreads();
    for (int i = t; i < PA_CHUNK; i += 1024) {   // coalesced-run copy-out
        unsigned r = ord[i];
        unsigned bd = r >> 24;
        unsigned pos = gbase[bd] + ((unsigned)i - lstart[bd]);
        if (pos < ECAP) ebuf[bd * ECAP + pos] = r;
        unsigned s = sord[i];
        unsigned bs = 256 + (s >> 8);
        unsigned pos2 = gbase[bs] + ((unsigned)i - lstart[bs]);
        if (pos2 < SCAP) sbuf[(size_t)(bs - 256) * SCAP + pos2] = (unsigned short)s;
    }
}

// Stage 1b: one block per bucket (R2-verified structure; scan upgraded to the
// 3-barrier shfl form verified in R4/R6). Per-node dst counts (-> deg_in) AND
// src counts from sbuf (-> deg_out), both coalesced. 8-padded exclusive scan
// -> off (16B-aligned uint4 CSR segments), scatter src u16s into an LDS CSR
// tile, copy out coalesced.
__global__ void __launch_bounds__(1024) sortB_kernel(
        const unsigned* __restrict__ gcur, const unsigned* __restrict__ ebuf,
        const unsigned short* __restrict__ sbuf,
        int* __restrict__ deg_out, int* __restrict__ deg_in,
        int* __restrict__ off, unsigned short* __restrict__ csr) {
    __shared__ unsigned eb[ECAP];              // 20 KB
    __shared__ unsigned short csr_l[CCAP];     // 12 KB
    __shared__ unsigned dcount[256], dcur[256], scount[256];
    __shared__ unsigned wsum8[8];
    __shared__ unsigned tot_s;
    int b = blockIdx.x;
    int t = threadIdx.x;
    unsigned cntd = gcur[b];      if (cntd > ECAP) cntd = ECAP;
    unsigned cnts = gcur[NB + b]; if (cnts > SCAP) cnts = SCAP;
    if (t < 256) { dcount[t] = 0; scount[t] = 0; }
    __syncthreads();
    const unsigned* __restrict__ sg = ebuf + (size_t)b * ECAP;
    for (int i = t; i < (int)cntd; i += 1024) {
        unsigned r = sg[i];
        eb[i] = r;
        atomicAdd(&dcount[(r >> 16) & 255u], 1u);
    }
    const unsigned short* __restrict__ ss = sbuf + (size_t)b * SCAP;
    for (int i = t; i < (int)cnts; i += 1024)
        atomicAdd(&scount[ss[i] & 255u], 1u);
    __syncthreads();
    // ---- 3-barrier shfl scan of 8-padded sizes (threads 0..255 = 4 waves) ----
    unsigned pad = 0, incl = 0;
    if (t < 256) {
        pad = (dcount[t] + 7u) & ~7u;
        incl = pad;
        int lane = t & 63;
#pragma unroll
        for (int st = 1; st < 64; st <<= 1) {
            unsigned u = __shfl_up(incl, st, 64);
            if (lane >= st) incl += u;
        }
        if (lane == 63) wsum8[t >> 6] = incl;
    }
    __syncthreads();
    if (t < 256) {
        int w = t >> 6;
        unsigned base = 0;
        for (int k = 0; k < w; ++k) base += wsum8[k];
        incl += base;
        unsigned ex = incl - pad;               // exclusive padded
        dcur[t] = ex;
        if (t == 255) tot_s = incl;
        int n = b * 256 + t;
        if (n < N_NODES) {
            deg_in[n]  = (int)dcount[t];
            deg_out[n] = (int)scount[t];
            off[n] = b * CCAP + (int)ex;
        }
    }
    __syncthreads();
    for (int i = t; i < (int)cntd; i += 1024) {   // CSR scatter from LDS stage
        unsigned r = eb[i];
        unsigned p = atomicAdd(&dcur[(r >> 16) & 255u], 1u);
        if (p < CCAP) csr_l[p] = (unsigned short)(r & 0xFFFFu);
    }
    __syncthreads();
    unsigned tot = tot_s;
    if (tot > CCAP) tot = CCAP;
    unsigned* __restrict__ og = (unsigned*)(csr + (size_t)b * CCAP);
    const unsigned* __restrict__ cl = (const unsigned*)csr_l;
    for (int i = t; i < (int)(tot >> 1); i += 1024) og[i] = cl[i];
}

// Stage 2: sfeat[s] = bf16_rtne(rsqrt(max(out_deg,1)) * feat[s]) (row-major),
// with the W transpose (WT[n][k] = bf16(W[k][n])) folded into the tail blocks.
// UNCHANGED from the 138.8us run.
__global__ void __launch_bounds__(256) conv_kernel(
        const float4* __restrict__ feat4, const int* __restrict__ deg_out,
        uint4* __restrict__ sfeat, const float* __restrict__ W,
        unsigned* __restrict__ WT32) {
    int blk = blockIdx.x;
    if (blk >= CONV_BLOCKS) {   // wprep tail
        int t = (blk - CONV_BLOCKS) * 256 + threadIdx.x;
        if (t >= D * (D / 2)) return;
        int n = t / (D / 2);
        int j = t - n * (D / 2);
        float w0 = W[(2 * j) * D + n];
        float w1 = W[(2 * j + 1) * D + n];
        WT32[n * (D / 2) + j] = bf16pack(w0, w1);
        return;
    }
    int t = blk * 256 + threadIdx.x;
    if (t >= N_NODES * RL) return;
    int n = t / RL;
    int lane = t - n * RL;
    float c = rsqrtf(fmaxf((float)deg_out[n], 1.0f));
    float4 a = feat4[n * D4 + lane * 2];
    float4 b = feat4[n * D4 + lane * 2 + 1];
    uint4 o;
    o.x = bf16pack(a.x * c, a.y * c);
    o.y = bf16pack(a.z * c, a.w * c);
    o.z = bf16pack(b.x * c, b.y * c);
    o.w = bf16pack(b.z * c, b.w * c);
    sfeat[t] = o;
}

// Stage 3 (fused gather+MFMA): UNCHANGED from the 138.8us run. One block =
// one 16-row tile, 192 threads (16 nodes x 12 lanes), 16-deep row prefetch,
// then 3 waves x 2 col-tiles of mfma_f32_16x16x32_bf16 + bias, fp32 store.
// Layouts (m89/m91-verified): A[m=lane&15][k=quad*8+j]; B[k=quad*8+j][n=lane&15];
// D col=lane&15, row=quad*4+reg.
__global__ void __launch_bounds__(192) gather_mm_kernel(
        const float4* __restrict__ feat4, const uint4* __restrict__ sfeat,
        const int* __restrict__ deg_in, const int* __restrict__ off,
        const unsigned short* __restrict__ csr, const uint4* __restrict__ wt4,
        const float* __restrict__ bias, float* __restrict__ out) {
    __shared__ uint4 sh[16 * HPAD];   // 3.25 KB
    int tid = threadIdx.x;
    {   // ---- gather phase ----
        int g = tid / RL;            // node 0..15
        int lane = tid - g * RL;     // uint4 index 0..11 (8 bf16)
        int n = blockIdx.x * 16 + g; // 3125*16 = 50000 exact
        int deg = deg_in[n];
        uint4* __restrict__ hout = &sh[g * HPAD + lane];
        if (deg == 0) {
            float4 a = feat4[n * D4 + lane * 2];
            float4 b = feat4[n * D4 + lane * 2 + 1];
            uint4 o;
            o.x = bf16pack(a.x, a.y);
            o.y = bf16pack(a.z, a.w);
            o.z = bf16pack(b.x, b.y);
            o.w = bf16pack(b.z, b.w);
            *hout = o;
        } else {
            const unsigned short* __restrict__ bk = csr + off[n];
            const uint4* __restrict__ sf = sfeat + lane;
            float acc[8] = {};
#define ACC8(v)  { \
        acc[0] += __uint_as_float((v).x << 16); \
        acc[1] += __uint_as_float((v).x & 0xFFFF0000u); \
        acc[2] += __uint_as_float((v).y << 16); \
        acc[3] += __uint_as_float((v).y & 0xFFFF0000u); \
        acc[4] += __uint_as_float((v).z << 16); \
        acc[5] += __uint_as_float((v).z & 0xFFFF0000u); \
        acc[6] += __uint_as_float((v).w << 16); \
        acc[7] += __uint_as_float((v).w & 0xFFFF0000u); }
            int i = 0;
            int full16 = deg & ~15;
            for (; i < full16; i += 16) {
                uint4 ia = *(const uint4*)(bk + i);       // 8 u16 indices
                uint4 ib = *(const uint4*)(bk + i + 8);   // 8 more
                unsigned s0 = ia.x & 0xFFFFu, s1 = ia.x >> 16;
                unsigned s2 = ia.y & 0xFFFFu, s3 = ia.y >> 16;
                unsigned s4 = ia.z & 0xFFFFu, s5 = ia.z >> 16;
                unsigned s6 = ia.w & 0xFFFFu, s7 = ia.w >> 16;
                unsigned s8 = ib.x & 0xFFFFu, s9 = ib.x >> 16;
                unsigned sa = ib.y & 0xFFFFu, sb = ib.y >> 16;
                unsigned sx = ib.z & 0xFFFFu, sd = ib.z >> 16;
                unsigned se = ib.w & 0xFFFFu, sfi = ib.w >> 16;
                uint4 v0 = sf[(size_t)s0 * RL];
                uint4 v1 = sf[(size_t)s1 * RL];
                uint4 v2 = sf[(size_t)s2 * RL];
                uint4 v3 = sf[(size_t)s3 * RL];
                uint4 v4 = sf[(size_t)s4 * RL];
                uint4 v5 = sf[(size_t)s5 * RL];
                uint4 v6 = sf[(size_t)s6 * RL];
                uint4 v7 = sf[(size_t)s7 * RL];
                uint4 v8 = sf[(size_t)s8 * RL];
                uint4 v9 = sf[(size_t)s9 * RL];
                uint4 va = sf[(size_t)sa * RL];
                uint4 vb = sf[(size_t)sb * RL];
                uint4 vc = sf[(size_t)sx * RL];
                uint4 vd = sf[(size_t)sd * RL];
                uint4 ve = sf[(size_t)se * RL];
                uint4 vf = sf[(size_t)sfi * RL];
                ACC8(v0); ACC8(v1); ACC8(v2); ACC8(v3);
                ACC8(v4); ACC8(v5); ACC8(v6); ACC8(v7);
                ACC8(v8); ACC8(v9); ACC8(va); ACC8(vb);
                ACC8(vc); ACC8(vd); ACC8(ve); ACC8(vf);
            }
            int full8 = deg & ~7;
            for (; i < full8; i += 8) {
                uint4 idx = *(const uint4*)(bk + i);
                unsigned s0 = idx.x & 0xFFFFu, s1 = idx.x >> 16;
                unsigned s2 = idx.y & 0xFFFFu, s3 = idx.y >> 16;
                unsigned s4 = idx.z & 0xFFFFu, s5 = idx.z >> 16;
                unsigned s6 = idx.w & 0xFFFFu, s7 = idx.w >> 16;
                uint4 v0 = sf[(size_t)s0 * RL];
                uint4 v1 = sf[(size_t)s1 * RL];
                uint4 v2 = sf[(size_t)s2 * RL];
                uint4 v3 = sf[(size_t)s3 * RL];
                uint4 v4 = sf[(size_t)s4 * RL];
                uint4 v5 = sf[(size_t)s5 * RL];
                uint4 v6 = sf[(size_t)s6 * RL];
                uint4 v7 = sf[(size_t)s7 * RL];
                ACC8(v0); ACC8(v1); ACC8(v2); ACC8(v3);
                ACC8(v4); ACC8(v5); ACC8(v6); ACC8(v7);
            }
            for (; i < deg; ++i) {
                uint4 v = sf[(size_t)bk[i] * RL];
                ACC8(v);
            }
#undef ACC8
            float cj = rsqrtf((float)deg);
            uint4 o;
            o.x = bf16pack(acc[0] * cj, acc[1] * cj);
            o.y = bf16pack(acc[2] * cj, acc[3] * cj);
            o.z = bf16pack(acc[4] * cj, acc[5] * cj);
            o.w = bf16pack(acc[6] * cj, acc[7] * cj);
            *hout = o;
        }
    }
    __syncthreads();
    // ---- MFMA phase ----
    int wave = tid >> 6;
    int lane = tid & 63;
    int m = lane & 15, quad = lane >> 4;
    short8 a0 = as_short8(sh[m * HPAD + quad]);       // k = 0..31
    short8 a1 = as_short8(sh[m * HPAD + 4 + quad]);   // k = 32..63
    short8 a2 = as_short8(sh[m * HPAD + 8 + quad]);   // k = 64..95
    int row0 = blockIdx.x * 16;
    int r_out0 = row0 + quad * 4;
#pragma unroll
    for (int ct = wave * 2; ct < wave * 2 + 2; ++ct) {
        int n = ct * 16 + m;
        int wb = n * RL + quad;
        short8 b0 = as_short8(wt4[wb]);
        short8 b1 = as_short8(wt4[wb + 4]);
        short8 b2 = as_short8(wt4[wb + 8]);
        floatx4 c = {0.f, 0.f, 0.f, 0.f};
        c = __builtin_amdgcn_mfma_f32_16x16x32_bf16(a0, b0, c, 0, 0, 0);
        c = __builtin_amdgcn_mfma_f32_16x16x32_bf16(a1, b1, c, 0, 0, 0);
        c = __builtin_amdgcn_mfma_f32_16x16x32_bf16(a2, b2, c, 0, 0, 0);
        float bs = bias[n];
#pragma unroll
        for (int r = 0; r < 4; ++r)
            out[(size_t)(r_out0 + r) * D + n] = c[r] + bs;
    }
}

extern "C" void kernel_launch(void* const* d_in, const int* in_sizes, int n_in,
                              void* d_out, int out_size, void* d_ws, size_t ws_size,
                              hipStream_t stream) {
    const float* feat = (const float*)d_in[0];
    const float* W    = (const float*)d_in[1];
    const float* bias = (const float*)d_in[2];
    const int*   src  = (const int*)d_in[3];
    const int*   dst  = (const int*)d_in[4];

    // ws layout (~18.8 MB; every byte rewritten each call or never read):
    //   gcur[2*NB] | deg_out[N] | deg_in[N] | off[N] |
    //   ebuf u32 [NB][ECAP] 4.0MB | sbuf u16 [NB][SCAP] 2.0MB |
    //   csr u16 [NB][CCAP] 2.4MB | sfeat 9.6MB | WT 18KB
    unsigned*       gcur    = (unsigned*)d_ws;
    int*            deg_out = (int*)(gcur + 2 * NB);
    int*            deg_in  = deg_out + N_NODES;
    int*            off     = deg_in + N_NODES;
    unsigned*       ebuf    = (unsigned*)(off + N_NODES);
    unsigned short* sbuf    = (unsigned short*)(ebuf + (size_t)NB * ECAP);
    unsigned short* csr     = sbuf + (size_t)NB * SCAP;
    uint4*          sfeat   = (uint4*)(csr + (size_t)NB * CCAP);
    unsigned*       WT32    = (unsigned*)(sfeat + (size_t)N_NODES * RL);

    hipMemsetAsync(gcur, 0, 2 * NB * sizeof(unsigned), stream);
    sortA_kernel<<<PA_BLOCKS, 1024, 0, stream>>>(src, dst, gcur, ebuf, sbuf);
    sortB_kernel<<<NB, 1024, 0, stream>>>(gcur, ebuf, sbuf, deg_out, deg_in, off, csr);
    conv_kernel<<<CONV_BLOCKS + WPREP_BLOCKS, 256, 0, stream>>>(
        (const float4*)feat, deg_out, sfeat, W, WT32);
    gather_mm_kernel<<<N_NODES / 16, 192, 0, stream>>>(
        (const float4*)feat, sfeat, deg_in, off, csr, (const uint4*)WT32,
        bias, (float*)d_out);
}